// Round 4
// baseline (17342.577 us; speedup 1.0000x reference)
//
#include <hip/hip_runtime.h>

typedef float v2f __attribute__((ext_vector_type(2)));

#define HID 32
#define LOG2E 1.4426950408889634f

#if __has_builtin(__builtin_amdgcn_exp2f)
#define EXP2(x) __builtin_amdgcn_exp2f(x)
#else
#define EXP2(x) exp2f(x)
#endif
#if __has_builtin(__builtin_amdgcn_rcpf)
#define RCP(x) __builtin_amdgcn_rcpf(x)
#else
#define RCP(x) (1.0f / (x))
#endif

// packed fp32 fma via builtin (compiler-scheduled, AGPR-capable operands)
#define PKFMA(acc, w, h) (acc) = __builtin_elementwise_fma((w), (h), (acc))

// LDS weight stream layout: 4 role blocks. Role p = units p*8..p*8+7.
// Per (unit u, gate g): 36 floats = [4 W_ih row floats][32 W_hh row floats].
// ROLE_W = 8*4*36 + 4 pad = 1156 words -> role bases hit banks {0,4,8,12}:
// the 4 concurrent role reads (16-lane broadcast each) are conflict-free.
#define ROLE_W 1156
// h exchange row stride: 36 floats (+4 pad) -> e and e+8 share a bank = 2-way (free)
#define HROW 36

// Quarter-wave layout: lane = (role p = lane>>4, element e = lane&15).
// 16 elements/wave -> 4096 waves -> 4 waves/SIMD; waves_per_eu(4) caps regs
// at 128 so all 4 are resident (a 3-wave limit would strand the 4th block).
__global__ __attribute__((amdgpu_waves_per_eu(4))) __launch_bounds__(256)
void lstm_qwave(const float* __restrict__ poses,
                const float* __restrict__ W_ih,
                const float* __restrict__ W_hh,
                const float* __restrict__ W_dense,
                float* __restrict__ out,
                int B, int T_enc, int T_dec)
{
    __shared__ __align__(16) float wlds[4 * ROLE_W + 64];  // weights + W_dense rows 1,2
    __shared__ __align__(16) float hbuf[4][16 * HROW];     // per-wave h exchange

    const int tid  = threadIdx.x;
    const int wv   = tid >> 6;
    const int lane = tid & 63;

    // ---- stage weights into per-role streams (once) ----
    for (int idx = tid; idx < 4 * HID * HID; idx += 256) {   // W_hh: [128][32]
        const int r = idx >> 5, c = idx & 31;
        const int g = r >> 5, k = r & 31, p = k >> 3, u = k & 7;
        wlds[p * ROLE_W + (u * 4 + g) * 36 + 4 + c] = W_hh[idx];
    }
    for (int idx = tid; idx < 4 * HID * 4; idx += 256) {     // W_ih: [128][4]
        const int r = idx >> 2, c = idx & 3;
        const int g = r >> 5, k = r & 31, p = k >> 3, u = k & 7;
        wlds[p * ROLE_W + (u * 4 + g) * 36 + c] = W_ih[idx];
    }
    for (int idx = tid; idx < 64; idx += 256)
        wlds[4 * ROLE_W + idx] = W_dense[HID + idx];         // rows 1 (v1), 2 (v2)
    for (int idx = lane; idx < 16 * HROW; idx += 64)
        hbuf[wv][idx] = 0.f;                                 // h0 = 0
    __syncthreads();                                         // the only barrier

    const int p  = lane >> 4;           // role: units p*8..p*8+7
    const int e  = lane & 15;           // element within wave
    const int el = (blockIdx.x * 4 + wv) * 16 + e;

    const float* __restrict__ wrole = &wlds[p * ROLE_W];
    const float* __restrict__ wd    = &wlds[4 * ROLE_W];
    float* __restrict__ hrow        = &hbuf[wv][e * HROW];   // my element's h row

    float c_[8];
    #pragma unroll
    for (int u = 0; u < 8; ++u) c_[u] = 0.f;

    const float4* poses4 = reinterpret_cast<const float4*>(poses);
    float4*       out4   = reinterpret_cast<float4*>(out);

    v2f h2[16];
    // broadcast-load my element's full h (8x ds_read_b128, 2-way = free)
    auto loadh = [&]() {
        const float4* hr4 = reinterpret_cast<const float4*>(hrow);
        #pragma unroll
        for (int j = 0; j < 8; ++j) {
            const float4 v = hr4[j];
            h2[2 * j]     = (v2f){v.x, v.y};
            h2[2 * j + 1] = (v2f){v.z, v.w};
        }
    };

    // one LSTM step. All 4 gates lane-local: no shfl, no cndmask, no
    // redundant halves. Wave-synchronous LDS h-exchange: no barriers.
    auto step = [&](v2f x01, v2f x23) {
        loadh();
        float hnew[8];
        #pragma unroll
        for (int u = 0; u < 8; ++u) {
            const v2f* w0 = reinterpret_cast<const v2f*>(wrole + u * 144);       // i
            const v2f* w1 = reinterpret_cast<const v2f*>(wrole + u * 144 + 36);  // f
            const v2f* w2 = reinterpret_cast<const v2f*>(wrole + u * 144 + 72);  // g
            const v2f* w3 = reinterpret_cast<const v2f*>(wrole + u * 144 + 108); // o
            v2f a0 = w0[0] * x01; PKFMA(a0, w0[1], x23);
            v2f a1 = w1[0] * x01; PKFMA(a1, w1[1], x23);
            v2f a2 = w2[0] * x01; PKFMA(a2, w2[1], x23);
            v2f a3 = w3[0] * x01; PKFMA(a3, w3[1], x23);
            #pragma unroll
            for (int j = 0; j < 16; ++j) {       // 4 independent pk chains
                PKFMA(a0, w0[2 + j], h2[j]);
                PKFMA(a1, w1[2 + j], h2[j]);
                PKFMA(a2, w2[2 + j], h2[j]);
                PKFMA(a3, w3[2 + j], h2[j]);
            }
            const float ai = a0.x + a0.y, af = a1.x + a1.y;
            const float ag = a2.x + a2.y, ao = a3.x + a3.y;
            const float i_ = RCP(1.0f + EXP2(-LOG2E * ai));
            const float f_ = RCP(1.0f + EXP2(-LOG2E * af));
            const float g_ = fmaf(-2.0f, RCP(1.0f + EXP2((2.0f * LOG2E) * ag)), 1.0f);
            const float o_ = RCP(1.0f + EXP2(-LOG2E * ao));
            c_[u] = fmaf(f_, c_[u], i_ * g_);
            const float th = fmaf(-2.0f, RCP(1.0f + EXP2((2.0f * LOG2E) * c_[u])), 1.0f);
            hnew[u] = o_ * th;
        }
        // publish my 8 units (2x ds_write_b128; 16B-aligned: e*144 + p*32)
        float4* hw = reinterpret_cast<float4*>(hrow + p * 8);
        hw[0] = make_float4(hnew[0], hnew[1], hnew[2], hnew[3]);
        hw[1] = make_float4(hnew[4], hnew[5], hnew[6], hnew[7]);
    };

    // velocity rows 1,2 of h @ W_dense.T (wd reads are whole-wave broadcast)
    float v1, v2;
    auto velocity = [&]() {
        loadh();
        const v2f* wdp = reinterpret_cast<const v2f*>(wd);
        v2f s1 = {0.f, 0.f}, s2 = {0.f, 0.f};
        #pragma unroll
        for (int j = 0; j < 16; ++j) {
            PKFMA(s1, wdp[j],      h2[j]);
            PKFMA(s2, wdp[16 + j], h2[j]);
        }
        v1 = s1.x + s1.y; v2 = s2.x + s2.y;
    };

    // ---------------- encoder (x prefetched one step ahead) ----------------
    float4 x = poses4[el];
    for (int t = 0; t < T_enc; ++t) {
        float4 xn = x;
        if (t + 1 < T_enc) xn = poses4[(size_t)(t + 1) * B + el];
        step((v2f){x.x, x.y}, (v2f){x.z, x.w});
        x = xn;
    }
    const v2f p01 = {x.x, x.y};          // poses[-1][:,:2], constant in decode

    velocity();

    // ---------------- decoder ----------------
    for (int t = 0; t < T_dec; ++t) {
        const float rn = rsqrtf(v1 * v1 + v2 * v2);
        const float cs = v1 * rn, sn = v2 * rn;
        if (p == 0) out4[(size_t)t * B + el] = make_float4(p01.x, p01.y, cs, sn);
        step(p01, (v2f){cs, sn});
        velocity();
    }
}

extern "C" void kernel_launch(void* const* d_in, const int* in_sizes, int n_in,
                              void* d_out, int out_size, void* d_ws, size_t ws_size,
                              hipStream_t stream) {
    const float* poses   = (const float*)d_in[0];
    // d_in[1] = deltas: values unused by the reference decoder (only length matters)
    const float* W_ih    = (const float*)d_in[2];
    const float* W_hh    = (const float*)d_in[3];
    const float* W_dense = (const float*)d_in[4];
    float* out = (float*)d_out;

    const int T_enc = 64;                       // fixed by the reference setup
    const int B     = in_sizes[0] / (T_enc * 4);
    const int T_dec = out_size / (B * 4);       // n_new_poses

    dim3 grid(B / 64), block(256);              // 16 elements/wave, 4 waves/block
    hipLaunchKernelGGL(lstm_qwave, grid, block, 0, stream,
                       poses, W_ih, W_hh, W_dense, out, B, T_enc, T_dec);
}

// Round 5
// 1435.696 us; speedup vs baseline: 12.0796x; 12.0796x over previous
//
#include <hip/hip_runtime.h>

typedef float v2f __attribute__((ext_vector_type(2)));

#define HID 32
#define LOG2E 1.4426950408889634f

#if __has_builtin(__builtin_amdgcn_exp2f)
#define EXP2(x) __builtin_amdgcn_exp2f(x)
#else
#define EXP2(x) exp2f(x)
#endif
#if __has_builtin(__builtin_amdgcn_rcpf)
#define RCP(x) __builtin_amdgcn_rcpf(x)
#else
#define RCP(x) (1.0f / (x))
#endif

// packed fp32 fma via builtin (compiler-scheduled, ACC-capable operands)
#define PKFMA(acc, w, h) (acc) = __builtin_elementwise_fma((w), (h), (acc))

// xor-butterfly add within 32-lane groups (each group holds every hidden unit
// exactly once, so both halves converge to the same full sum independently)
#define SWZ_ADD(p, imm) do {                                            \
    int _t = __builtin_amdgcn_ds_swizzle(__float_as_int(p), (imm));     \
    (p) += __int_as_float(_t); } while (0)
#define REDUCE32(p) do {                                                \
    SWZ_ADD(p, 0x041F); SWZ_ADD(p, 0x081F); SWZ_ADD(p, 0x101F);        \
    SWZ_ADD(p, 0x201F); SWZ_ADD(p, 0x401F); } while (0)

// waves_per_eu(2,2): pin EXACTLY 2 waves/SIMD -> 256-reg budget per wave.
// R4 lesson: a min-bound without a max lets the allocator chase occupancy
// and spill (waves_per_eu(4) alone -> 64 regs, h2 in scratch, 40 GB fetch).
// Here ~195 live regs fit with slack; weights provably arch-resident.
__global__ __attribute__((amdgpu_waves_per_eu(2, 2))) __launch_bounds__(256)
void lstm_dual(const float* __restrict__ poses,
               const float* __restrict__ W_ih,
               const float* __restrict__ W_hh,
               const float* __restrict__ W_dense,
               float* __restrict__ out,
               int B, int T_enc, int T_dec)
{
    // two elements per wave; hx row pair is wave-private -> NO barriers
    __shared__ __align__(16) float hx[4][2][HID];

    const int tid  = threadIdx.x;
    const int lane = tid & 63;
    const int wv   = tid >> 6;          // wave within block (0..3)
    const int k    = lane & 31;         // hidden unit
    const int isH  = lane >> 5;         // 0: rows {k,64+k}=(i,g); 1: {32+k,96+k}=(f,o)
    const int el0  = (blockIdx.x * 4 + wv) * 2;   // this wave's two elements
    const int el1  = el0 + 1;

    const int rowA = isH * 32 + k;      // i or f
    const int rowB = rowA + 64;         // g or o

    // ---- persistent weights: 72 floats/lane, shared by both elements ----
    const v2f* Wih2 = reinterpret_cast<const v2f*>(W_ih);
    v2f wA0 = Wih2[2 * rowA], wA1 = Wih2[2 * rowA + 1];
    v2f wB0 = Wih2[2 * rowB], wB1 = Wih2[2 * rowB + 1];
    v2f whhA[16], whhB[16];
    {
        const v2f* Whh2 = reinterpret_cast<const v2f*>(W_hh);
        #pragma unroll
        for (int j = 0; j < 16; ++j) {
            whhA[j] = Whh2[rowA * 16 + j];
            whhB[j] = Whh2[rowB * 16 + j];
        }
    }
    const float wd1 = W_dense[HID + k];
    const float wd2 = W_dense[2 * HID + k];

    // branchless activation selectors: rowA always sigmoid; rowB tanh|sigmoid
    const float S1 = isH ? -LOG2E : 2.0f * LOG2E;
    const float A1 = isH ? 0.0f : 1.0f;
    const float B1 = isH ? 1.0f : -2.0f;

    v2f h2a[16], h2b[16];
    #pragma unroll
    for (int j = 0; j < 16; ++j) { h2a[j] = (v2f){0.f, 0.f}; h2b[j] = (v2f){0.f, 0.f}; }
    float c0 = 0.f, c1 = 0.f, hk0 = 0.f, hk1 = 0.f;

    const float4* poses4 = reinterpret_cast<const float4*>(poses);
    float4*       out4   = reinterpret_cast<float4*>(out);

    float* __restrict__ hrow = &hx[wv][0][0];   // 64 floats: [elem0 32][elem1 32]

    // gate finish for one element (both halves duplicate c/h: no extra shfl)
    auto finish = [&](v2f aA, v2f aB, float& c, float& hk) {
        const float a0 = aA.x + aA.y;       // i or f pre-activation
        const float a1 = aB.x + aB.y;       // g or o pre-activation
        const float act0 = RCP(1.0f + EXP2(-LOG2E * a0));          // sigmoid
        const float act1 = fmaf(B1, RCP(1.0f + EXP2(S1 * a1)), A1);
        const float xo0 = __shfl_xor(act0, 32, 64);
        const float xo1 = __shfl_xor(act1, 32, 64);
        const float i_ = isH ? xo0  : act0;
        const float f_ = isH ? act0 : xo0;
        const float g_ = isH ? xo1  : act1;
        const float o_ = isH ? act1 : xo1;
        c = fmaf(f_, c, i_ * g_);
        const float th = fmaf(-2.0f, RCP(1.0f + EXP2((2.0f * LOG2E) * c)), 1.0f);
        hk = o_ * th;                       // identical in lanes k and k+32
    };

    // one LSTM step for BOTH elements: 4 independent pk chains share weights
    auto step = [&](v2f aA0, v2f aB0, v2f aA1, v2f aB1) {
        #pragma unroll
        for (int j = 0; j < 16; ++j) {
            PKFMA(aA0, whhA[j], h2a[j]);
            PKFMA(aB0, whhB[j], h2a[j]);
            PKFMA(aA1, whhA[j], h2b[j]);
            PKFMA(aB1, whhB[j], h2b[j]);
        }
        finish(aA0, aB0, c0, hk0);
        finish(aA1, aB1, c1, hk1);
        // publish: one full-wave contiguous ds_write_b32 (addr = lane), since
        // isH*32+k == lane: half0 writes elem0's unit k, half1 elem1's.
        hrow[lane] = isH ? hk1 : hk0;
        // broadcast read-back (wave-synchronous, compiler inserts lgkmcnt)
        const v2f* hr = reinterpret_cast<const v2f*>(hrow);
        #pragma unroll
        for (int j = 0; j < 16; ++j) { h2a[j] = hr[j]; h2b[j] = hr[16 + j]; }
    };

    // ---------------- encoder (x prefetched one step ahead) ----------------
    const float4* pp = poses4 + el0;        // wave-uniform addresses
    float4 x0 = pp[0], x1 = pp[1];
    for (int t = 0; t < T_enc; ++t) {
        pp += B;
        float4 xn0 = x0, xn1 = x1;
        if (t + 1 < T_enc) { xn0 = pp[0]; xn1 = pp[1]; }
        v2f aA0 = {0.f, 0.f}, aB0 = {0.f, 0.f}, aA1 = {0.f, 0.f}, aB1 = {0.f, 0.f};
        const v2f x001 = {x0.x, x0.y}, x023 = {x0.z, x0.w};
        const v2f x101 = {x1.x, x1.y}, x123 = {x1.z, x1.w};
        PKFMA(aA0, wA0, x001); PKFMA(aA0, wA1, x023);
        PKFMA(aB0, wB0, x001); PKFMA(aB0, wB1, x023);
        PKFMA(aA1, wA0, x101); PKFMA(aA1, wA1, x123);
        PKFMA(aB1, wB0, x101); PKFMA(aB1, wB1, x123);
        step(aA0, aB0, aA1, aB1);
        x0 = xn0; x1 = xn1;
    }
    const v2f p001 = {x0.x, x0.y};          // poses[-1][:,:2] per element
    const v2f p101 = {x1.x, x1.y};

    float v10 = wd1 * hk0, v20 = wd2 * hk0;     // vel rows 1,2 (row 0 unused)
    float v11 = wd1 * hk1, v21 = wd2 * hk1;
    REDUCE32(v10); REDUCE32(v20); REDUCE32(v11); REDUCE32(v21);

    // decode x-part: p01 contribution is loop-invariant -> hoist
    v2f bA0 = {0.f, 0.f}, bB0 = {0.f, 0.f}, bA1 = {0.f, 0.f}, bB1 = {0.f, 0.f};
    PKFMA(bA0, wA0, p001); PKFMA(bB0, wB0, p001);
    PKFMA(bA1, wA0, p101); PKFMA(bB1, wB0, p101);

    // ---------------- decoder ----------------
    for (int t = 0; t < T_dec; ++t) {
        const float rn0 = rsqrtf(v10 * v10 + v20 * v20);
        const float cs0 = v10 * rn0, sn0 = v20 * rn0;
        const float rn1 = rsqrtf(v11 * v11 + v21 * v21);
        const float cs1 = v11 * rn1, sn1 = v21 * rn1;
        if (lane == 0) out4[(size_t)t * B + el0] = make_float4(p001.x, p001.y, cs0, sn0);
        if (lane == 1) out4[(size_t)t * B + el1] = make_float4(p101.x, p101.y, cs1, sn1);
        v2f aA0 = bA0, aB0 = bB0, aA1 = bA1, aB1 = bB1;
        const v2f cssn0 = {cs0, sn0}, cssn1 = {cs1, sn1};
        PKFMA(aA0, wA1, cssn0); PKFMA(aB0, wB1, cssn0);
        PKFMA(aA1, wA1, cssn1); PKFMA(aB1, wB1, cssn1);
        step(aA0, aB0, aA1, aB1);
        v10 = wd1 * hk0; v20 = wd2 * hk0;
        v11 = wd1 * hk1; v21 = wd2 * hk1;
        REDUCE32(v10); REDUCE32(v20); REDUCE32(v11); REDUCE32(v21);
    }
}

extern "C" void kernel_launch(void* const* d_in, const int* in_sizes, int n_in,
                              void* d_out, int out_size, void* d_ws, size_t ws_size,
                              hipStream_t stream) {
    const float* poses   = (const float*)d_in[0];
    // d_in[1] = deltas: values unused by the reference decoder (only length matters)
    const float* W_ih    = (const float*)d_in[2];
    const float* W_hh    = (const float*)d_in[3];
    const float* W_dense = (const float*)d_in[4];
    float* out = (float*)d_out;

    const int T_enc = 64;                       // fixed by the reference setup
    const int B     = in_sizes[0] / (T_enc * 4);
    const int T_dec = out_size / (B * 4);       // n_new_poses

    dim3 grid(B / 8), block(256);               // 2 elements/wave, 4 waves/block
    hipLaunchKernelGGL(lstm_dual, grid, block, 0, stream,
                       poses, W_ih, W_hh, W_dense, out, B, T_enc, T_dec);
}